// Round 5
// baseline (373.998 us; speedup 1.0000x reference)
//
#include <hip/hip_runtime.h>
#include <cstdint>
#include <cstddef>

// Problem constants (fixed by reference setup_inputs)
#define BATCH 8
#define CH    128
#define NPTS  65536
#define NOBJ  64
#define SEGEL (CH * NOBJ)      // 8192 partial elements per block

// ---- sort-based main path geometry ----
#define TPB2  512              // 8 waves
#define PPB2  1024             // points per block
#define NCH2  (NPTS / PPB2)    // 64 chunks per batch -> 512 blocks
#define WSL   1152             // padded wave buffer: 1024 + 1024/8 words

// Monotonic order-preserving encode: larger float -> larger uint.
// Encoded 0 only arises from -NaN, so 0 is a safe empty sentinel.
__device__ __forceinline__ uint32_t enc_f32(float f) {
    uint32_t x = __float_as_uint(f);
    return x ^ ((uint32_t)((int32_t)x >> 31) | 0x80000000u);
}
__device__ __forceinline__ float dec_f32(uint32_t u) {
    uint32_t x = u ^ ((uint32_t)((int32_t)(~u) >> 31) | 0x80000000u);
    return __uint_as_float(x);
}

// ---------------------------------------------------------------------------
// seg_max_sort: counting-sort points by seg once per block (box_idx is
// channel-invariant), then per channel: coalesced load -> ds_write scatter
// into seg-sorted order (wave-private buffer, no barriers) -> contiguous
// ds_read windows -> register fmax pre-combine along runs -> LDS atomic only
// at run boundaries (~1.9 per 16 values vs 16). DS atomic pipe measured at
// ~1 lane-op/cyc/CU (R3/R4: 262K lane-atomics/CU == ~109us) -> cut lane-ops 8x.
// ---------------------------------------------------------------------------
__global__ __launch_bounds__(TPB2) void seg_max_sort(
        const float* __restrict__ pf,     // (B, C, N)
        const int*   __restrict__ bidx,   // (B, N)
        uint32_t*    __restrict__ ws)     // (B*NCH2, SEGEL) encoded partials
{
    __shared__ float    wavebuf[8 * WSL];    // 36 KiB, per-wave sorted values
    __shared__ uint32_t dest[PPB2];          // point -> sorted slot
    __shared__ uint32_t slotseg[PPB2];       // sorted slot -> seg
    __shared__ uint32_t cnt[NOBJ];
    __shared__ uint32_t off[NOBJ];
    __shared__ uint32_t accbuf[8 * NOBJ];    // per-wave per-seg partials

    const int tid = threadIdx.x;
    const int w   = tid >> 6;                // wave 0..7
    const int l   = tid & 63;                // lane
    const int b     = blockIdx.x / NCH2;
    const int chunk = blockIdx.x % NCH2;
    const int n0    = chunk * PPB2;

    // ---- phase 0a: count segs (once) ----
    if (tid < NOBJ) cnt[tid] = 0u;
    __syncthreads();
    const int2 sv = *(const int2*)(bidx + (size_t)b * NPTS + n0 + tid * 2);
    const uint32_t r0 = atomicAdd(&cnt[sv.x], 1u);
    const uint32_t r1 = atomicAdd(&cnt[sv.y], 1u);
    __syncthreads();

    // ---- phase 0b: exclusive scan of counts (wave 0) ----
    if (tid < 64) {
        const uint32_t c = cnt[tid];
        uint32_t inc = c;
        #pragma unroll
        for (int d = 1; d < 64; d <<= 1) {
            const uint32_t t = __shfl_up(inc, d, 64);
            if (tid >= d) inc += t;
        }
        off[tid] = inc - c;
    }
    __syncthreads();

    // ---- phase 0c: dest (bijection) + slot->seg map ----
    const uint32_t d0 = off[sv.x] + r0;
    const uint32_t d1 = off[sv.y] + r1;
    dest[tid * 2]     = d0;
    dest[tid * 2 + 1] = d1;
    slotseg[d0] = (uint32_t)sv.x;
    slotseg[d1] = (uint32_t)sv.y;
    __syncthreads();

    // ---- phase 0d: round-invariant per-thread metadata into registers ----
    // Scatter dests for this thread's 16 load positions (padded word index).
    uint32_t pdest[16];
    #pragma unroll
    for (int j = 0; j < 4; ++j) {
        const uint4 dd = *(const uint4*)&dest[j * 256 + l * 4];
        pdest[j * 4 + 0] = dd.x + (dd.x >> 3);
        pdest[j * 4 + 1] = dd.y + (dd.y >> 3);
        pdest[j * 4 + 2] = dd.z + (dd.z >> 3);
        pdest[j * 4 + 3] = dd.w + (dd.w >> 3);
    }
    // Window (16 contiguous sorted slots at l*16): segs + run-boundary mask.
    uint32_t seg16[16];
    #pragma unroll
    for (int j = 0; j < 4; ++j) {
        const uint4 ss = *(const uint4*)&slotseg[l * 16 + j * 4];
        seg16[j * 4 + 0] = ss.x;  seg16[j * 4 + 1] = ss.y;
        seg16[j * 4 + 2] = ss.z;  seg16[j * 4 + 3] = ss.w;
    }
    uint32_t mask = 0x8000u;                 // always emit at window end
    #pragma unroll
    for (int j = 0; j < 15; ++j)
        mask |= (seg16[j] != seg16[j + 1] ? 1u : 0u) << j;
    uint32_t wsp[4];                          // packed segs, 8b each
    #pragma unroll
    for (int q = 0; q < 4; ++q)
        wsp[q] = seg16[q*4] | (seg16[q*4+1] << 8) | (seg16[q*4+2] << 16) | (seg16[q*4+3] << 24);

    // ---- main loop: wave w handles channel cb + w; no barriers ----
    const float* pbase = pf + (size_t)b * CH * NPTS + n0;
    float*    bw  = wavebuf + w * WSL;
    uint32_t* acc = accbuf + w * NOBJ;
    uint32_t* wsb = ws + (size_t)blockIdx.x * SEGEL;

    float4 v[4], vn[4];
    {
        const float* pc = pbase + (size_t)w * NPTS;
        #pragma unroll
        for (int j = 0; j < 4; ++j) v[j] = *(const float4*)(pc + j * 256 + l * 4);
    }

    for (int cb = 0; cb < CH; cb += 8) {
        const int c = cb + w;
        const bool more = (cb + 8 < CH);
        if (more) {   // prefetch next round (block-uniform branch)
            const float* pn = pbase + (size_t)(c + 8) * NPTS;
            #pragma unroll
            for (int j = 0; j < 4; ++j) vn[j] = *(const float4*)(pn + j * 256 + l * 4);
        }

        acc[l] = 0u;                          // init this round's partials

        // scatter into seg-sorted order (wave-private, plain writes)
        #pragma unroll
        for (int j = 0; j < 4; ++j) {
            bw[pdest[j * 4 + 0]] = v[j].x;
            bw[pdest[j * 4 + 1]] = v[j].y;
            bw[pdest[j * 4 + 2]] = v[j].z;
            bw[pdest[j * 4 + 3]] = v[j].w;
        }

        // contiguous window read (conflict-free via pad) + run pre-combine
        const int base = l * 18;              // l*16 padded
        float m = -INFINITY;
        #pragma unroll
        for (int j = 0; j < 16; ++j) {
            const float x = bw[base + j + (j >> 3)];
            m = fmaxf(m, x);
            if ((mask >> j) & 1u) {
                const uint32_t seg = (wsp[j >> 2] >> ((j & 3) * 8)) & 0xFFu;
                atomicMax(&acc[seg], enc_f32(m));
                m = -INFINITY;
            }
        }

        // dump wave partials (coalesced, 64 dwords)
        wsb[(size_t)c * NOBJ + l] = acc[l];

        if (more) {
            #pragma unroll
            for (int j = 0; j < 4; ++j) v[j] = vn[j];
        }
    }
}

// Max over per-chunk partials + decode + finite guard. Writes every output
// element exactly once.
template <int NCHUNK>
__global__ __launch_bounds__(256) void reduce_ws(
        const uint32_t* __restrict__ ws, float* __restrict__ out)
{
    const int g = blockIdx.x * 256 + threadIdx.x;   // 0 .. B*SEGEL-1
    const int b = g >> 13;                          // SEGEL = 8192
    const int e = g & (SEGEL - 1);
    const uint32_t* p = ws + (size_t)b * NCHUNK * SEGEL + e;
    uint32_t m = 0u;
    #pragma unroll
    for (int k = 0; k < NCHUNK; ++k) m = max(m, p[(size_t)k * SEGEL]);
    const int c   = e >> 6;
    const int seg = e & 63;
    float f = 0.0f;
    if (m) { f = dec_f32(m); if (!isfinite(f)) f = 0.0f; }
    out[(size_t)(b * NOBJ + seg) * CH + c] = f;
}

// ---------------------------------------------------------------------------
// Fallback path (ws too small): LDS-atomic accumulate + global-atomic merge.
// ---------------------------------------------------------------------------
__global__ __launch_bounds__(256) void init_out_kernel(uint32_t* __restrict__ out, int n) {
    int i = blockIdx.x * blockDim.x + threadIdx.x;
    if (i < n) out[i] = 0u;
}

__global__ __launch_bounds__(256) void seg_max_atomic(
        const float* __restrict__ pf, const int* __restrict__ bidx,
        uint32_t* __restrict__ out)
{
    constexpr int PPB = 1024;
    __shared__ uint32_t acc[SEGEL];
    const int tid   = threadIdx.x;
    const int b     = blockIdx.x / (NPTS / PPB);
    const int chunk = blockIdx.x % (NPTS / PPB);
    const int n0    = chunk * PPB;
    for (int i = tid; i < SEGEL; i += 256) acc[i] = 0u;
    __syncthreads();
    const int4 sv = *(const int4*)(bidx + (size_t)b * NPTS + n0 + tid * 4);
    const float* p = pf + (size_t)b * CH * NPTS + n0 + tid * 4;
    uint32_t* row = acc;
    #pragma unroll 4
    for (int c = 0; c < CH; ++c, p += NPTS, row += NOBJ) {
        const float4 v = *(const float4*)p;
        atomicMax(&row[sv.x], enc_f32(v.x));
        atomicMax(&row[sv.y], enc_f32(v.y));
        atomicMax(&row[sv.z], enc_f32(v.z));
        atomicMax(&row[sv.w], enc_f32(v.w));
    }
    __syncthreads();
    for (int e = tid; e < SEGEL; e += 256) {
        const int seg = e & (NOBJ - 1);
        const int c   = e >> 6;
        const uint32_t v = acc[c * NOBJ + seg];
        if (v) atomicMax(&out[(size_t)(b * NOBJ + seg) * CH + c], v);
    }
}

__global__ __launch_bounds__(256) void finalize_kernel(uint32_t* __restrict__ out, int n) {
    int i = blockIdx.x * blockDim.x + threadIdx.x;
    if (i >= n) return;
    const uint32_t u = out[i];
    float f = 0.0f;
    if (u) { f = dec_f32(u); if (!isfinite(f)) f = 0.0f; }
    ((float*)out)[i] = f;
}

extern "C" void kernel_launch(void* const* d_in, const int* in_sizes, int n_in,
                              void* d_out, int out_size, void* d_ws, size_t ws_size,
                              hipStream_t stream) {
    const float* pf   = (const float*)d_in[0];
    const int*   bidx = (const int*)d_in[1];

    const size_t need = (size_t)BATCH * NCH2 * SEGEL * 4;   // 16 MiB

    if (ws_size >= need) {
        uint32_t* ws = (uint32_t*)d_ws;
        seg_max_sort<<<BATCH * NCH2, TPB2, 0, stream>>>(pf, bidx, ws);
        reduce_ws<NCH2><<<(BATCH * SEGEL) / 256, 256, 0, stream>>>(ws, (float*)d_out);
    } else {
        uint32_t* out = (uint32_t*)d_out;
        init_out_kernel<<<(out_size + 255) / 256, 256, 0, stream>>>(out, out_size);
        seg_max_atomic<<<BATCH * (NPTS / 1024), 256, 0, stream>>>(pf, bidx, out);
        finalize_kernel<<<(out_size + 255) / 256, 256, 0, stream>>>(out, out_size);
    }
}